// Round 2
// baseline (312.694 us; speedup 1.0000x reference)
//
#include <hip/hip_runtime.h>
#include <math.h>

#define DIM 128
#define HEADS 8
#define HD 16
#define NPOS 8192      // 32*32*8
#define EPS 1e-5f

// ---------------- instance-norm stats ----------------
// blocks 0..127   : x channels   (1024 elems each)
// blocks 128..255 : skip channels (8192 elems each)
// ws layout: [0,128) mu_x  [128,256) rs_x  [256,384) mu_s  [384,512) rs_s
__global__ __launch_bounds__(256) void stats_kernel(const float* __restrict__ x,
                                                    const float* __restrict__ skip,
                                                    float* __restrict__ ws) {
    int c = blockIdx.x;
    const float* src; int n; float* mu_out; float* rs_out; int ci;
    if (c < DIM) { ci = c; src = x + c * 1024; n = 1024; mu_out = ws; rs_out = ws + DIM; }
    else { ci = c - DIM; src = skip + (size_t)ci * NPOS; n = NPOS; mu_out = ws + 2*DIM; rs_out = ws + 3*DIM; }
    int t = threadIdx.x;
    float s = 0.f, s2 = 0.f;
    for (int i = t; i < n; i += 256) { float v = src[i]; s += v; s2 = fmaf(v, v, s2); }
    #pragma unroll
    for (int off = 32; off > 0; off >>= 1) {
        s  += __shfl_down(s,  off, 64);
        s2 += __shfl_down(s2, off, 64);
    }
    __shared__ float ls[4], ls2[4];
    int wv = t >> 6;
    if ((t & 63) == 0) { ls[wv] = s; ls2[wv] = s2; }
    __syncthreads();
    if (t == 0) {
        float S  = ls[0] + ls[1] + ls[2] + ls[3];
        float S2 = ls2[0] + ls2[1] + ls2[2] + ls2[3];
        float inv_n = 1.f / (float)n;
        float mu  = S * inv_n;
        float var = S2 * inv_n - mu * mu;
        mu_out[ci] = mu;
        rs_out[ci] = rsqrtf(var + EPS);
    }
}

// ---------------- q/k/v projections ----------------
// grid (128, 3), 512 threads: blockIdx.x = 64-position tile, blockIdx.y = {q,k,v}
// thread t: ln = t&63 (position), ch = t>>6 (8 groups); computes 16 consecutive out channels.
__global__ __launch_bounds__(512) void qkv_kernel(const float* __restrict__ x,
                                                  const float* __restrict__ skip,
                                                  const float* __restrict__ Wq, const float* __restrict__ bq,
                                                  const float* __restrict__ Wk, const float* __restrict__ bk,
                                                  const float* __restrict__ Wv, const float* __restrict__ bv,
                                                  const float* __restrict__ ws,
                                                  float* __restrict__ q_out,
                                                  float* __restrict__ k_out,
                                                  float* __restrict__ v_out) {
    __shared__ float a[64 * 129];
    int t = threadIdx.x;
    int which = blockIdx.y;
    int n0 = blockIdx.x * 64;

    if (which == 0) {
        const float* mu = ws;       const float* rs = ws + DIM;
        for (int idx = t; idx < 8192; idx += 512) {
            int ci = idx >> 6, ln = idx & 63;
            int n = n0 + ln;
            int hc = n >> 8, wc = (n >> 3) & 31, zc = n & 7;
            float v = x[ci * 1024 + (hc >> 1) * 64 + (wc >> 1) * 4 + (zc >> 1)];
            a[ln * 129 + ci] = (v - mu[ci]) * rs[ci];
        }
    } else {
        const float* mu = ws + 2*DIM; const float* rs = ws + 3*DIM;
        for (int idx = t; idx < 8192; idx += 512) {
            int ci = idx >> 6, ln = idx & 63;
            float v = skip[(size_t)ci * NPOS + n0 + ln];
            a[ln * 129 + ci] = (v - mu[ci]) * rs[ci];
        }
    }
    __syncthreads();

    const float* W  = (which == 0) ? Wq : (which == 1) ? Wk : Wv;
    const float* b  = (which == 0) ? bq : (which == 1) ? bk : bv;
    float* outp     = (which == 0) ? q_out : (which == 1) ? k_out : v_out;
    float scale     = (which == 0) ? 0.25f : 1.0f;   // HEAD_DIM^-0.5

    int ln = t & 63, ch = t >> 6;   // ch in 0..7, wave-uniform -> W loads broadcast
    float acc[16];
    #pragma unroll
    for (int j = 0; j < 16; ++j) acc[j] = b[ch * 16 + j];
    for (int ci = 0; ci < 128; ++ci) {
        float av = a[ln * 129 + ci];
        const float4* wr = (const float4*)(W + ci * 128 + ch * 16);
        #pragma unroll
        for (int j4 = 0; j4 < 4; ++j4) {
            float4 w4 = wr[j4];
            acc[j4*4 + 0] = fmaf(av, w4.x, acc[j4*4 + 0]);
            acc[j4*4 + 1] = fmaf(av, w4.y, acc[j4*4 + 1]);
            acc[j4*4 + 2] = fmaf(av, w4.z, acc[j4*4 + 2]);
            acc[j4*4 + 3] = fmaf(av, w4.w, acc[j4*4 + 3]);
        }
    }
    float* op = outp + (size_t)(n0 + ln) * 128 + ch * 16;
    #pragma unroll
    for (int j = 0; j < 16; j += 4) {
        float4 vv = make_float4(acc[j] * scale, acc[j+1] * scale, acc[j+2] * scale, acc[j+3] * scale);
        *(float4*)(op + j) = vv;
    }
}

// ---------------- neighborhood attention ----------------
// 8 lanes per (n, head): each lane handles neighbors j = r, r+8, ... < 125 with a
// private online softmax, then a 3-step shfl_xor butterfly merges (m, l, o[16]).
// 524288 threads = 8192 waves (vs 1024 in v1).
__global__ __launch_bounds__(256) void attn_kernel(const float* __restrict__ q,
                                                   const float* __restrict__ k,
                                                   const float* __restrict__ v,
                                                   const float* __restrict__ rpb,
                                                   float* __restrict__ ao) {
    int g = blockIdx.x * 256 + threadIdx.x;
    int r = g & 7;            // neighbor slot
    int h = (g >> 3) & 7;     // head
    int n = g >> 6;           // position
    int hc = n >> 8, wc = (n >> 3) & 31, zc = n & 7;

    float qv[16];
    #pragma unroll
    for (int i = 0; i < 4; ++i)
        ((float4*)qv)[i] = ((const float4*)(q + (size_t)n * 128 + h * 16))[i];

    float o[16];
    #pragma unroll
    for (int d = 0; d < 16; ++d) o[d] = 0.f;
    float m = -1e30f, l = 0.f;

    int sh = min(max(hc - 2, 0), 27);
    int sw = min(max(wc - 2, 0), 27);
    int sz = min(max(zc - 2, 0), 3);
    const float* rp = rpb + h * 729 + (sh - hc + 4) * 81 + (sw - wc + 4) * 9 + (sz - zc + 4);

    for (int j = r; j < 125; j += 8) {
        int jh = j / 25;
        int jr = j - jh * 25;
        int jw = jr / 5;
        int jz = jr - jw * 5;
        int nbr = (sh + jh) * 256 + (sw + jw) * 8 + (sz + jz);
        float bias = rp[jh * 81 + jw * 9 + jz];
        const float* kp = k + (size_t)nbr * 128 + h * 16;
        const float* vp = v + (size_t)nbr * 128 + h * 16;
        float kv[16], vv[16];
        #pragma unroll
        for (int i = 0; i < 4; ++i) ((float4*)kv)[i] = ((const float4*)kp)[i];
        #pragma unroll
        for (int i = 0; i < 4; ++i) ((float4*)vv)[i] = ((const float4*)vp)[i];
        float d0 = 0.f, d1 = 0.f, d2 = 0.f, d3 = 0.f;
        #pragma unroll
        for (int d = 0; d < 4; ++d) {
            d0 = fmaf(qv[d],      kv[d],      d0);
            d1 = fmaf(qv[d + 4],  kv[d + 4],  d1);
            d2 = fmaf(qv[d + 8],  kv[d + 8],  d2);
            d3 = fmaf(qv[d + 12], kv[d + 12], d3);
        }
        float s = (d0 + d1) + (d2 + d3) + bias;
        float mn = fmaxf(m, s);
        float sc = __expf(m - mn);
        float p  = __expf(s - mn);
        l = fmaf(l, sc, p);
        #pragma unroll
        for (int d = 0; d < 16; ++d) o[d] = fmaf(o[d], sc, p * vv[d]);
        m = mn;
    }

    // butterfly merge across the 8 slots (adjacent lanes)
    #pragma unroll
    for (int step = 1; step <= 4; step <<= 1) {
        float m2 = __shfl_xor(m, step, 64);
        float l2 = __shfl_xor(l, step, 64);
        float mn = fmaxf(m, m2);
        float a = __expf(m - mn);
        float b = __expf(m2 - mn);
        l = l * a + l2 * b;
        #pragma unroll
        for (int d = 0; d < 16; ++d) {
            float od = __shfl_xor(o[d], step, 64);
            o[d] = o[d] * a + od * b;
        }
        m = mn;
    }
    float inv = 1.f / l;
    // all 8 lanes hold the full (n,h) result; lane r stores dims [2r, 2r+2)
    float2 res = make_float2(o[2 * r] * inv, o[2 * r + 1] * inv);
    *(float2*)(ao + (size_t)n * 128 + h * 16 + 2 * r) = res;
}

// ---------------- output projection + transpose to (C, H, W, Z) ----------------
__global__ __launch_bounds__(512) void proj_kernel(const float* __restrict__ ao,
                                                   const float* __restrict__ Wo,
                                                   const float* __restrict__ bo,
                                                   float* __restrict__ out) {
    __shared__ float a[64 * 129];
    int t = threadIdx.x;
    int n0 = blockIdx.x * 64;
    for (int idx = t; idx < 8192; idx += 512) {
        int ln = idx >> 7, ci = idx & 127;
        a[ln * 129 + ci] = ao[(size_t)n0 * 128 + idx];
    }
    __syncthreads();

    int ln = t & 63, ch = t >> 6;
    float acc[16];
    #pragma unroll
    for (int j = 0; j < 16; ++j) acc[j] = bo[ch * 16 + j];
    for (int ci = 0; ci < 128; ++ci) {
        float av = a[ln * 129 + ci];
        const float4* wr = (const float4*)(Wo + ci * 128 + ch * 16);
        #pragma unroll
        for (int j4 = 0; j4 < 4; ++j4) {
            float4 w4 = wr[j4];
            acc[j4*4 + 0] = fmaf(av, w4.x, acc[j4*4 + 0]);
            acc[j4*4 + 1] = fmaf(av, w4.y, acc[j4*4 + 1]);
            acc[j4*4 + 2] = fmaf(av, w4.z, acc[j4*4 + 2]);
            acc[j4*4 + 3] = fmaf(av, w4.w, acc[j4*4 + 3]);
        }
    }
    // out[c][n] : lanes (ln) consecutive in n -> coalesced stores
    #pragma unroll
    for (int j = 0; j < 16; ++j)
        out[(size_t)(ch * 16 + j) * NPOS + n0 + ln] = acc[j];
}

extern "C" void kernel_launch(void* const* d_in, const int* in_sizes, int n_in,
                              void* d_out, int out_size, void* d_ws, size_t ws_size,
                              hipStream_t stream) {
    const float* x    = (const float*)d_in[0];
    const float* skip = (const float*)d_in[1];
    const float* Wq   = (const float*)d_in[2];
    const float* bq   = (const float*)d_in[3];
    const float* Wk   = (const float*)d_in[4];
    const float* bk   = (const float*)d_in[5];
    const float* Wv   = (const float*)d_in[6];
    const float* bv   = (const float*)d_in[7];
    const float* rpb  = (const float*)d_in[8];
    const float* Wo   = (const float*)d_in[9];
    const float* bo   = (const float*)d_in[10];
    float* out = (float*)d_out;

    float* ws  = (float*)d_ws;            // 512 floats of norm stats
    float* q   = ws + 512;                // 8192*128
    float* k   = q  + (size_t)NPOS * 128; // 8192*128
    float* v   = k  + (size_t)NPOS * 128; // 8192*128
    float* ao  = v  + (size_t)NPOS * 128; // 8192*128

    stats_kernel<<<256, 256, 0, stream>>>(x, skip, ws);
    qkv_kernel<<<dim3(128, 3), 512, 0, stream>>>(x, skip, Wq, bq, Wk, bk, Wv, bv, ws, q, k, v);
    attn_kernel<<<2048, 256, 0, stream>>>(q, k, v, rpb, ao);
    proj_kernel<<<128, 512, 0, stream>>>(ao, Wo, bo, out);
}

// Round 3
// 215.485 us; speedup vs baseline: 1.4511x; 1.4511x over previous
//
#include <hip/hip_runtime.h>
#include <math.h>

#define DIM 128
#define HEADS 8
#define HD 16
#define NPOS 8192      // 32*32*8
#define EPS 1e-5f

// ---------------- instance-norm stats ----------------
__global__ __launch_bounds__(256) void stats_kernel(const float* __restrict__ x,
                                                    const float* __restrict__ skip,
                                                    float* __restrict__ ws) {
    int c = blockIdx.x;
    const float* src; int n; float* mu_out; float* rs_out; int ci;
    if (c < DIM) { ci = c; src = x + c * 1024; n = 1024; mu_out = ws; rs_out = ws + DIM; }
    else { ci = c - DIM; src = skip + (size_t)ci * NPOS; n = NPOS; mu_out = ws + 2*DIM; rs_out = ws + 3*DIM; }
    int t = threadIdx.x;
    float s = 0.f, s2 = 0.f;
    for (int i = t; i < n; i += 256) { float v = src[i]; s += v; s2 = fmaf(v, v, s2); }
    #pragma unroll
    for (int off = 32; off > 0; off >>= 1) {
        s  += __shfl_down(s,  off, 64);
        s2 += __shfl_down(s2, off, 64);
    }
    __shared__ float ls[4], ls2[4];
    int wv = t >> 6;
    if ((t & 63) == 0) { ls[wv] = s; ls2[wv] = s2; }
    __syncthreads();
    if (t == 0) {
        float S  = ls[0] + ls[1] + ls[2] + ls[3];
        float S2 = ls2[0] + ls2[1] + ls2[2] + ls2[3];
        float inv_n = 1.f / (float)n;
        float mu  = S * inv_n;
        float var = S2 * inv_n - mu * mu;
        mu_out[ci] = mu;
        rs_out[ci] = rsqrtf(var + EPS);
    }
}

// ---------------- q/k/v projections ----------------
__global__ __launch_bounds__(512) void qkv_kernel(const float* __restrict__ x,
                                                  const float* __restrict__ skip,
                                                  const float* __restrict__ Wq, const float* __restrict__ bq,
                                                  const float* __restrict__ Wk, const float* __restrict__ bk,
                                                  const float* __restrict__ Wv, const float* __restrict__ bv,
                                                  const float* __restrict__ ws,
                                                  float* __restrict__ q_out,
                                                  float* __restrict__ k_out,
                                                  float* __restrict__ v_out) {
    __shared__ float a[64 * 129];
    int t = threadIdx.x;
    int which = blockIdx.y;
    int n0 = blockIdx.x * 64;

    if (which == 0) {
        const float* mu = ws;       const float* rs = ws + DIM;
        for (int idx = t; idx < 8192; idx += 512) {
            int ci = idx >> 6, ln = idx & 63;
            int n = n0 + ln;
            int hc = n >> 8, wc = (n >> 3) & 31, zc = n & 7;
            float v = x[ci * 1024 + (hc >> 1) * 64 + (wc >> 1) * 4 + (zc >> 1)];
            a[ln * 129 + ci] = (v - mu[ci]) * rs[ci];
        }
    } else {
        const float* mu = ws + 2*DIM; const float* rs = ws + 3*DIM;
        for (int idx = t; idx < 8192; idx += 512) {
            int ci = idx >> 6, ln = idx & 63;
            float v = skip[(size_t)ci * NPOS + n0 + ln];
            a[ln * 129 + ci] = (v - mu[ci]) * rs[ci];
        }
    }
    __syncthreads();

    const float* W  = (which == 0) ? Wq : (which == 1) ? Wk : Wv;
    const float* b  = (which == 0) ? bq : (which == 1) ? bk : bv;
    float* outp     = (which == 0) ? q_out : (which == 1) ? k_out : v_out;
    float scale     = (which == 0) ? 0.25f : 1.0f;

    int ln = t & 63, ch = t >> 6;
    float acc[16];
    #pragma unroll
    for (int j = 0; j < 16; ++j) acc[j] = b[ch * 16 + j];
    for (int ci = 0; ci < 128; ++ci) {
        float av = a[ln * 129 + ci];
        const float4* wr = (const float4*)(W + ci * 128 + ch * 16);
        #pragma unroll
        for (int j4 = 0; j4 < 4; ++j4) {
            float4 w4 = wr[j4];
            acc[j4*4 + 0] = fmaf(av, w4.x, acc[j4*4 + 0]);
            acc[j4*4 + 1] = fmaf(av, w4.y, acc[j4*4 + 1]);
            acc[j4*4 + 2] = fmaf(av, w4.z, acc[j4*4 + 2]);
            acc[j4*4 + 3] = fmaf(av, w4.w, acc[j4*4 + 3]);
        }
    }
    float* op = outp + (size_t)(n0 + ln) * 128 + ch * 16;
    #pragma unroll
    for (int j = 0; j < 16; j += 4) {
        float4 vv = make_float4(acc[j] * scale, acc[j+1] * scale, acc[j+2] * scale, acc[j+3] * scale);
        *(float4*)(op + j) = vv;
    }
}

// ---------------- neighborhood attention: LDS-tiled ----------------
// Block = (4x4x8 position tile, head). Halo = 8x8x8 = 512 neighbors.
// k/v head-slices staged in LDS quad-major: kq[d4][512][4] so compute-phase
// ds_read_b128 chunks are uniformly spread mod 8 bank-quads (conflict-free).
// 4 lanes per position, each a private online softmax over j == s (mod 4),
// iterated in a lane-rotated order (i0 = p&31) to spread LDS chunks; merged
// with a 2-step shfl_xor butterfly.
__global__ __launch_bounds__(512) void attn_kernel(const float* __restrict__ q,
                                                   const float* __restrict__ k,
                                                   const float* __restrict__ v,
                                                   const float* __restrict__ rpb,
                                                   float* __restrict__ ao) {
    __shared__ float kq[4 * 512 * 4];   // 32 KB
    __shared__ float vq[4 * 512 * 4];   // 32 KB
    __shared__ float qT[128 * 20];      // 10 KB (row stride 20: 5 coprime 8)
    __shared__ float bias_l[729];       // ~2.9 KB

    int blk = blockIdx.x;
    int h    = blk & 7;
    int tile = blk >> 3;
    int h0 = (tile >> 3) * 4;
    int w0 = (tile & 7) * 4;
    int bh0 = min(max(h0 - 2, 0), 24);
    int bw0 = min(max(w0 - 2, 0), 24);
    int t = threadIdx.x;

    // ---- stage k, v halo (512 nbrs x 16 floats each) ----
    for (int idx = t; idx < 2048; idx += 512) {
        int nbr = idx >> 2, d4 = idx & 3;
        int nh = bh0 + (nbr >> 6);
        int nw = bw0 + ((nbr >> 3) & 7);
        int nz = nbr & 7;
        int n  = nh * 256 + nw * 8 + nz;
        float4 kk = *(const float4*)(k + (size_t)n * 128 + h * 16 + d4 * 4);
        float4 vv = *(const float4*)(v + (size_t)n * 128 + h * 16 + d4 * 4);
        *(float4*)(kq + (d4 * 512 + nbr) * 4) = kk;
        *(float4*)(vq + (d4 * 512 + nbr) * 4) = vv;
    }
    // ---- stage q tile (128 positions x 16 floats) ----
    {
        int p = t >> 2, d4 = t & 3;
        int n = (h0 + (p >> 5)) * 256 + (w0 + ((p >> 3) & 3)) * 8 + (p & 7);
        float4 qq = *(const float4*)(q + (size_t)n * 128 + h * 16 + d4 * 4);
        *(float4*)(qT + p * 20 + d4 * 4) = qq;
    }
    // ---- stage bias slice ----
    for (int idx = t; idx < 729; idx += 512) bias_l[idx] = rpb[h * 729 + idx];
    __syncthreads();

    int s = t & 3, p = t >> 2;
    int ph = p >> 5, pw = (p >> 3) & 3, pz = p & 7;
    int hc = h0 + ph, wc = w0 + pw, zc = pz;
    int sh = min(max(hc - 2, 0), 27);
    int sw = min(max(wc - 2, 0), 27);
    int sz = min(max(zc - 2, 0), 3);
    int base_nbr  = (sh - bh0) * 64 + (sw - bw0) * 8 + sz;
    int bias_base = (sh - hc + 4) * 81 + (sw - wc + 4) * 9 + (sz - zc + 4);

    float qv[16];
    #pragma unroll
    for (int i = 0; i < 4; ++i) ((float4*)qv)[i] = *(const float4*)(qT + p * 20 + i * 4);

    float o[16];
    #pragma unroll
    for (int d = 0; d < 16; ++d) o[d] = 0.f;
    float m = -1e30f, l = 0.f;

    int cnt = (s == 0) ? 32 : 31;       // j = 4*ii + s covers 0..124
    int i0 = p & 31; if (i0 >= cnt) i0 -= cnt;

    for (int it = 0; it < cnt; ++it) {
        int ii = i0 + it; if (ii >= cnt) ii -= cnt;
        int j = ii * 4 + s;
        int jh = (j * 41) >> 10;        // j / 25
        int jr = j - jh * 25;
        int jw = (jr * 13) >> 6;        // jr / 5
        int jz = jr - jw * 5;
        int nbr = base_nbr + jh * 64 + jw * 8 + jz;
        float bias = bias_l[bias_base + jh * 81 + jw * 9 + jz];

        float kv[16], vv[16];
        #pragma unroll
        for (int d4 = 0; d4 < 4; ++d4) {
            ((float4*)kv)[d4] = *(const float4*)(kq + (d4 * 512 + nbr) * 4);
            ((float4*)vv)[d4] = *(const float4*)(vq + (d4 * 512 + nbr) * 4);
        }
        float d0 = 0.f, d1 = 0.f, d2 = 0.f, d3 = 0.f;
        #pragma unroll
        for (int d = 0; d < 4; ++d) {
            d0 = fmaf(qv[d],      kv[d],      d0);
            d1 = fmaf(qv[d + 4],  kv[d + 4],  d1);
            d2 = fmaf(qv[d + 8],  kv[d + 8],  d2);
            d3 = fmaf(qv[d + 12], kv[d + 12], d3);
        }
        float sc_ = (d0 + d1) + (d2 + d3) + bias;
        float mn = fmaxf(m, sc_);
        float a  = __expf(m - mn);
        float pp = __expf(sc_ - mn);
        l = fmaf(l, a, pp);
        #pragma unroll
        for (int d = 0; d < 16; ++d) o[d] = fmaf(o[d], a, pp * vv[d]);
        m = mn;
    }

    // ---- merge the 4 slots (lanes t&3) ----
    #pragma unroll
    for (int step = 1; step <= 2; step <<= 1) {
        float m2 = __shfl_xor(m, step, 64);
        float l2 = __shfl_xor(l, step, 64);
        float mn = fmaxf(m, m2);
        float a = __expf(m - mn);
        float b = __expf(m2 - mn);
        l = l * a + l2 * b;
        #pragma unroll
        for (int d = 0; d < 16; ++d) {
            float od = __shfl_xor(o[d], step, 64);
            o[d] = o[d] * a + od * b;
        }
        m = mn;
    }
    float inv = 1.f / l;
    int n = hc * 256 + wc * 8 + zc;
    float4 r = make_float4(o[4*s] * inv, o[4*s+1] * inv, o[4*s+2] * inv, o[4*s+3] * inv);
    *(float4*)(ao + (size_t)n * 128 + h * 16 + s * 4) = r;
}

// ---------------- output projection + transpose to (C, H, W, Z) ----------------
__global__ __launch_bounds__(512) void proj_kernel(const float* __restrict__ ao,
                                                   const float* __restrict__ Wo,
                                                   const float* __restrict__ bo,
                                                   float* __restrict__ out) {
    __shared__ float a[64 * 129];
    int t = threadIdx.x;
    int n0 = blockIdx.x * 64;
    for (int idx = t; idx < 8192; idx += 512) {
        int ln = idx >> 7, ci = idx & 127;
        a[ln * 129 + ci] = ao[(size_t)n0 * 128 + idx];
    }
    __syncthreads();

    int ln = t & 63, ch = t >> 6;
    float acc[16];
    #pragma unroll
    for (int j = 0; j < 16; ++j) acc[j] = bo[ch * 16 + j];
    for (int ci = 0; ci < 128; ++ci) {
        float av = a[ln * 129 + ci];
        const float4* wr = (const float4*)(Wo + ci * 128 + ch * 16);
        #pragma unroll
        for (int j4 = 0; j4 < 4; ++j4) {
            float4 w4 = wr[j4];
            acc[j4*4 + 0] = fmaf(av, w4.x, acc[j4*4 + 0]);
            acc[j4*4 + 1] = fmaf(av, w4.y, acc[j4*4 + 1]);
            acc[j4*4 + 2] = fmaf(av, w4.z, acc[j4*4 + 2]);
            acc[j4*4 + 3] = fmaf(av, w4.w, acc[j4*4 + 3]);
        }
    }
    #pragma unroll
    for (int j = 0; j < 16; ++j)
        out[(size_t)(ch * 16 + j) * NPOS + n0 + ln] = acc[j];
}

extern "C" void kernel_launch(void* const* d_in, const int* in_sizes, int n_in,
                              void* d_out, int out_size, void* d_ws, size_t ws_size,
                              hipStream_t stream) {
    const float* x    = (const float*)d_in[0];
    const float* skip = (const float*)d_in[1];
    const float* Wq   = (const float*)d_in[2];
    const float* bq   = (const float*)d_in[3];
    const float* Wk   = (const float*)d_in[4];
    const float* bk   = (const float*)d_in[5];
    const float* Wv   = (const float*)d_in[6];
    const float* bv   = (const float*)d_in[7];
    const float* rpb  = (const float*)d_in[8];
    const float* Wo   = (const float*)d_in[9];
    const float* bo   = (const float*)d_in[10];
    float* out = (float*)d_out;

    float* ws  = (float*)d_ws;
    float* q   = ws + 512;
    float* k   = q  + (size_t)NPOS * 128;
    float* v   = k  + (size_t)NPOS * 128;
    float* ao  = v  + (size_t)NPOS * 128;

    stats_kernel<<<256, 256, 0, stream>>>(x, skip, ws);
    qkv_kernel<<<dim3(128, 3), 512, 0, stream>>>(x, skip, Wq, bq, Wk, bk, Wv, bv, ws, q, k, v);
    attn_kernel<<<512, 512, 0, stream>>>(q, k, v, rpb, ao);
    proj_kernel<<<128, 512, 0, stream>>>(ao, Wo, bo, out);
}

// Round 4
// 149.665 us; speedup vs baseline: 2.0893x; 1.4398x over previous
//
#include <hip/hip_runtime.h>
#include <math.h>

#define DIM 128
#define HEADS 8
#define HD 16
#define NPOS 8192      // 32*32*8
#define EPS 1e-5f

// ---------------- instance-norm stats ----------------
__global__ __launch_bounds__(256) void stats_kernel(const float* __restrict__ x,
                                                    const float* __restrict__ skip,
                                                    float* __restrict__ ws) {
    int c = blockIdx.x;
    const float* src; int n; float* mu_out; float* rs_out; int ci;
    if (c < DIM) { ci = c; src = x + c * 1024; n = 1024; mu_out = ws; rs_out = ws + DIM; }
    else { ci = c - DIM; src = skip + (size_t)ci * NPOS; n = NPOS; mu_out = ws + 2*DIM; rs_out = ws + 3*DIM; }
    int t = threadIdx.x;
    float s = 0.f, s2 = 0.f;
    for (int i = t; i < n; i += 256) { float v = src[i]; s += v; s2 = fmaf(v, v, s2); }
    #pragma unroll
    for (int off = 32; off > 0; off >>= 1) {
        s  += __shfl_down(s,  off, 64);
        s2 += __shfl_down(s2, off, 64);
    }
    __shared__ float ls[4], ls2[4];
    int wv = t >> 6;
    if ((t & 63) == 0) { ls[wv] = s; ls2[wv] = s2; }
    __syncthreads();
    if (t == 0) {
        float S  = ls[0] + ls[1] + ls[2] + ls[3];
        float S2 = ls2[0] + ls2[1] + ls2[2] + ls2[3];
        float inv_n = 1.f / (float)n;
        float mu  = S * inv_n;
        float var = S2 * inv_n - mu * mu;
        mu_out[ci] = mu;
        rs_out[ci] = rsqrtf(var + EPS);
    }
}

// ---------------- q/k/v projections (W staged in LDS) ----------------
// grid (128, 3, 2): 64-pos tile x {q,k,v} x out-channel half.
// LDS: A 64x129 (33KB, conflict-free gather) + W-half 128x64 (32KB, broadcast
// reads) = 65.8KB -> 2 blocks/CU, 16 waves/CU.
// Thread: ln=t&63 (pos), ch=t>>6 (wave-uniform); computes 8 out channels.
__global__ __launch_bounds__(512) void qkv_kernel(const float* __restrict__ x,
                                                  const float* __restrict__ skip,
                                                  const float* __restrict__ Wq, const float* __restrict__ bq,
                                                  const float* __restrict__ Wk, const float* __restrict__ bk,
                                                  const float* __restrict__ Wv, const float* __restrict__ bv,
                                                  const float* __restrict__ ws,
                                                  float* __restrict__ q_out,
                                                  float* __restrict__ k_out,
                                                  float* __restrict__ v_out) {
    __shared__ float a[64 * 129];
    __shared__ float wl[128 * 64];
    int t = threadIdx.x;
    int which = blockIdx.y;
    int half  = blockIdx.z;
    int n0 = blockIdx.x * 64;

    const float* W = (which == 0) ? Wq : (which == 1) ? Wk : Wv;
    const float* b = (which == 0) ? bq : (which == 1) ? bk : bv;
    float* outp    = (which == 0) ? q_out : (which == 1) ? k_out : v_out;
    float scale    = (which == 0) ? 0.25f : 1.0f;

    // ---- stage W half: wl[ci][j] = W[ci][half*64 + j] ----
    {
        const float4* W4 = (const float4*)W;
        float4* wl4 = (float4*)wl;
        for (int i4 = t; i4 < 2048; i4 += 512) {
            int ci = i4 >> 4, j4 = i4 & 15;
            wl4[ci * 16 + j4] = W4[ci * 32 + half * 16 + j4];
        }
    }
    // ---- stage normalized A tile ----
    if (which == 0) {
        const float* mu = ws;       const float* rs = ws + DIM;
        for (int idx = t; idx < 8192; idx += 512) {
            int ci = idx >> 6, ln = idx & 63;
            int n = n0 + ln;
            int hc = n >> 8, wc = (n >> 3) & 31, zc = n & 7;
            float v = x[ci * 1024 + (hc >> 1) * 64 + (wc >> 1) * 4 + (zc >> 1)];
            a[ln * 129 + ci] = (v - mu[ci]) * rs[ci];
        }
    } else {
        const float* mu = ws + 2*DIM; const float* rs = ws + 3*DIM;
        for (int idx = t; idx < 8192; idx += 512) {
            int ci = idx >> 6, ln = idx & 63;
            float v = skip[(size_t)ci * NPOS + n0 + ln];
            a[ln * 129 + ci] = (v - mu[ci]) * rs[ci];
        }
    }
    __syncthreads();

    int ln = t & 63, ch = t >> 6;   // ch wave-uniform -> W reads broadcast
    float acc[8];
    #pragma unroll
    for (int j = 0; j < 8; ++j) acc[j] = b[half * 64 + ch * 8 + j];
    for (int ci = 0; ci < 128; ++ci) {
        float av = a[ln * 129 + ci];
        const float4* wr = (const float4*)(wl + ci * 64 + ch * 8);
        float4 w0 = wr[0], w1 = wr[1];
        acc[0] = fmaf(av, w0.x, acc[0]);
        acc[1] = fmaf(av, w0.y, acc[1]);
        acc[2] = fmaf(av, w0.z, acc[2]);
        acc[3] = fmaf(av, w0.w, acc[3]);
        acc[4] = fmaf(av, w1.x, acc[4]);
        acc[5] = fmaf(av, w1.y, acc[5]);
        acc[6] = fmaf(av, w1.z, acc[6]);
        acc[7] = fmaf(av, w1.w, acc[7]);
    }
    float* op = outp + (size_t)(n0 + ln) * 128 + half * 64 + ch * 8;
    *(float4*)(op + 0) = make_float4(acc[0]*scale, acc[1]*scale, acc[2]*scale, acc[3]*scale);
    *(float4*)(op + 4) = make_float4(acc[4]*scale, acc[5]*scale, acc[6]*scale, acc[7]*scale);
}

// ---------------- neighborhood attention: LDS-tiled ----------------
__global__ __launch_bounds__(512) void attn_kernel(const float* __restrict__ q,
                                                   const float* __restrict__ k,
                                                   const float* __restrict__ v,
                                                   const float* __restrict__ rpb,
                                                   float* __restrict__ ao) {
    __shared__ float kq[4 * 512 * 4];   // 32 KB
    __shared__ float vq[4 * 512 * 4];   // 32 KB
    __shared__ float qT[128 * 20];      // 10 KB
    __shared__ float bias_l[729];

    int blk = blockIdx.x;
    int h    = blk & 7;
    int tile = blk >> 3;
    int h0 = (tile >> 3) * 4;
    int w0 = (tile & 7) * 4;
    int bh0 = min(max(h0 - 2, 0), 24);
    int bw0 = min(max(w0 - 2, 0), 24);
    int t = threadIdx.x;

    for (int idx = t; idx < 2048; idx += 512) {
        int nbr = idx >> 2, d4 = idx & 3;
        int nh = bh0 + (nbr >> 6);
        int nw = bw0 + ((nbr >> 3) & 7);
        int nz = nbr & 7;
        int n  = nh * 256 + nw * 8 + nz;
        float4 kk = *(const float4*)(k + (size_t)n * 128 + h * 16 + d4 * 4);
        float4 vv = *(const float4*)(v + (size_t)n * 128 + h * 16 + d4 * 4);
        *(float4*)(kq + (d4 * 512 + nbr) * 4) = kk;
        *(float4*)(vq + (d4 * 512 + nbr) * 4) = vv;
    }
    {
        int p = t >> 2, d4 = t & 3;
        int n = (h0 + (p >> 5)) * 256 + (w0 + ((p >> 3) & 3)) * 8 + (p & 7);
        float4 qq = *(const float4*)(q + (size_t)n * 128 + h * 16 + d4 * 4);
        *(float4*)(qT + p * 20 + d4 * 4) = qq;
    }
    for (int idx = t; idx < 729; idx += 512) bias_l[idx] = rpb[h * 729 + idx];
    __syncthreads();

    int s = t & 3, p = t >> 2;
    int ph = p >> 5, pw = (p >> 3) & 3, pz = p & 7;
    int hc = h0 + ph, wc = w0 + pw, zc = pz;
    int sh = min(max(hc - 2, 0), 27);
    int sw = min(max(wc - 2, 0), 27);
    int sz = min(max(zc - 2, 0), 3);
    int base_nbr  = (sh - bh0) * 64 + (sw - bw0) * 8 + sz;
    int bias_base = (sh - hc + 4) * 81 + (sw - wc + 4) * 9 + (sz - zc + 4);

    float qv[16];
    #pragma unroll
    for (int i = 0; i < 4; ++i) ((float4*)qv)[i] = *(const float4*)(qT + p * 20 + i * 4);

    float o[16];
    #pragma unroll
    for (int d = 0; d < 16; ++d) o[d] = 0.f;
    float m = -1e30f, l = 0.f;

    int cnt = (s == 0) ? 32 : 31;
    int i0 = p & 31; if (i0 >= cnt) i0 -= cnt;

    for (int it = 0; it < cnt; ++it) {
        int ii = i0 + it; if (ii >= cnt) ii -= cnt;
        int j = ii * 4 + s;
        int jh = (j * 41) >> 10;
        int jr = j - jh * 25;
        int jw = (jr * 13) >> 6;
        int jz = jr - jw * 5;
        int nbr = base_nbr + jh * 64 + jw * 8 + jz;
        float bias = bias_l[bias_base + jh * 81 + jw * 9 + jz];

        float kv[16], vv[16];
        #pragma unroll
        for (int d4 = 0; d4 < 4; ++d4) {
            ((float4*)kv)[d4] = *(const float4*)(kq + (d4 * 512 + nbr) * 4);
            ((float4*)vv)[d4] = *(const float4*)(vq + (d4 * 512 + nbr) * 4);
        }
        float d0 = 0.f, d1 = 0.f, d2 = 0.f, d3 = 0.f;
        #pragma unroll
        for (int d = 0; d < 4; ++d) {
            d0 = fmaf(qv[d],      kv[d],      d0);
            d1 = fmaf(qv[d + 4],  kv[d + 4],  d1);
            d2 = fmaf(qv[d + 8],  kv[d + 8],  d2);
            d3 = fmaf(qv[d + 12], kv[d + 12], d3);
        }
        float sc_ = (d0 + d1) + (d2 + d3) + bias;
        float mn = fmaxf(m, sc_);
        float a  = __expf(m - mn);
        float pp = __expf(sc_ - mn);
        l = fmaf(l, a, pp);
        #pragma unroll
        for (int d = 0; d < 16; ++d) o[d] = fmaf(o[d], a, pp * vv[d]);
        m = mn;
    }

    #pragma unroll
    for (int step = 1; step <= 2; step <<= 1) {
        float m2 = __shfl_xor(m, step, 64);
        float l2 = __shfl_xor(l, step, 64);
        float mn = fmaxf(m, m2);
        float a = __expf(m - mn);
        float b = __expf(m2 - mn);
        l = l * a + l2 * b;
        #pragma unroll
        for (int d = 0; d < 16; ++d) {
            float od = __shfl_xor(o[d], step, 64);
            o[d] = o[d] * a + od * b;
        }
        m = mn;
    }
    float inv = 1.f / l;
    int n = hc * 256 + wc * 8 + zc;
    float4 r = make_float4(o[4*s] * inv, o[4*s+1] * inv, o[4*s+2] * inv, o[4*s+3] * inv);
    *(float4*)(ao + (size_t)n * 128 + h * 16 + s * 4) = r;
}

// ---------------- output projection (Wo staged in LDS) ----------------
// grid (128, 2): 64-pos tile x out-channel half. Same structure as qkv.
__global__ __launch_bounds__(512) void proj_kernel(const float* __restrict__ ao,
                                                   const float* __restrict__ Wo,
                                                   const float* __restrict__ bo,
                                                   float* __restrict__ out) {
    __shared__ float a[64 * 129];
    __shared__ float wl[128 * 64];
    int t = threadIdx.x;
    int half = blockIdx.y;
    int n0 = blockIdx.x * 64;

    {
        const float4* W4 = (const float4*)Wo;
        float4* wl4 = (float4*)wl;
        for (int i4 = t; i4 < 2048; i4 += 512) {
            int ci = i4 >> 4, j4 = i4 & 15;
            wl4[ci * 16 + j4] = W4[ci * 32 + half * 16 + j4];
        }
    }
    for (int idx = t; idx < 8192; idx += 512) {
        int ln = idx >> 7, ci = idx & 127;
        a[ln * 129 + ci] = ao[(size_t)n0 * 128 + idx];
    }
    __syncthreads();

    int ln = t & 63, ch = t >> 6;
    float acc[8];
    #pragma unroll
    for (int j = 0; j < 8; ++j) acc[j] = bo[half * 64 + ch * 8 + j];
    for (int ci = 0; ci < 128; ++ci) {
        float av = a[ln * 129 + ci];
        const float4* wr = (const float4*)(wl + ci * 64 + ch * 8);
        float4 w0 = wr[0], w1 = wr[1];
        acc[0] = fmaf(av, w0.x, acc[0]);
        acc[1] = fmaf(av, w0.y, acc[1]);
        acc[2] = fmaf(av, w0.z, acc[2]);
        acc[3] = fmaf(av, w0.w, acc[3]);
        acc[4] = fmaf(av, w1.x, acc[4]);
        acc[5] = fmaf(av, w1.y, acc[5]);
        acc[6] = fmaf(av, w1.z, acc[6]);
        acc[7] = fmaf(av, w1.w, acc[7]);
    }
    // out[c][n] : lanes (ln) consecutive in n -> coalesced stores
    #pragma unroll
    for (int j = 0; j < 8; ++j)
        out[(size_t)(half * 64 + ch * 8 + j) * NPOS + n0 + ln] = acc[j];
}

extern "C" void kernel_launch(void* const* d_in, const int* in_sizes, int n_in,
                              void* d_out, int out_size, void* d_ws, size_t ws_size,
                              hipStream_t stream) {
    const float* x    = (const float*)d_in[0];
    const float* skip = (const float*)d_in[1];
    const float* Wq   = (const float*)d_in[2];
    const float* bq   = (const float*)d_in[3];
    const float* Wk   = (const float*)d_in[4];
    const float* bk   = (const float*)d_in[5];
    const float* Wv   = (const float*)d_in[6];
    const float* bv   = (const float*)d_in[7];
    const float* rpb  = (const float*)d_in[8];
    const float* Wo   = (const float*)d_in[9];
    const float* bo   = (const float*)d_in[10];
    float* out = (float*)d_out;

    float* ws  = (float*)d_ws;
    float* q   = ws + 512;
    float* k   = q  + (size_t)NPOS * 128;
    float* v   = k  + (size_t)NPOS * 128;
    float* ao  = v  + (size_t)NPOS * 128;

    stats_kernel<<<256, 256, 0, stream>>>(x, skip, ws);
    qkv_kernel<<<dim3(128, 3, 2), 512, 0, stream>>>(x, skip, Wq, bq, Wk, bk, Wv, bv, ws, q, k, v);
    attn_kernel<<<512, 512, 0, stream>>>(q, k, v, rpb, ao);
    proj_kernel<<<dim3(128, 2), 512, 0, stream>>>(ao, Wo, bo, out);
}

// Round 5
// 147.668 us; speedup vs baseline: 2.1176x; 1.0135x over previous
//
#include <hip/hip_runtime.h>
#include <math.h>

#define DIM 128
#define HEADS 8
#define HD 16
#define NPOS 8192      // 32*32*8
#define EPS 1e-5f

// round-to-nearest-even fp32 -> bf16 (values are tame: no NaN/Inf handling)
static __device__ __forceinline__ unsigned short f2bf(float f) {
    unsigned u = __float_as_uint(f);
    return (unsigned short)((u + 0x7fffu + ((u >> 16) & 1u)) >> 16);
}

// ---------------- instance-norm stats ----------------
__global__ __launch_bounds__(256) void stats_kernel(const float* __restrict__ x,
                                                    const float* __restrict__ skip,
                                                    float* __restrict__ ws) {
    int c = blockIdx.x;
    const float* src; int n; float* mu_out; float* rs_out; int ci;
    if (c < DIM) { ci = c; src = x + c * 1024; n = 1024; mu_out = ws; rs_out = ws + DIM; }
    else { ci = c - DIM; src = skip + (size_t)ci * NPOS; n = NPOS; mu_out = ws + 2*DIM; rs_out = ws + 3*DIM; }
    int t = threadIdx.x;
    float s = 0.f, s2 = 0.f;
    for (int i = t; i < n; i += 256) { float v = src[i]; s += v; s2 = fmaf(v, v, s2); }
    #pragma unroll
    for (int off = 32; off > 0; off >>= 1) {
        s  += __shfl_down(s,  off, 64);
        s2 += __shfl_down(s2, off, 64);
    }
    __shared__ float ls[4], ls2[4];
    int wv = t >> 6;
    if ((t & 63) == 0) { ls[wv] = s; ls2[wv] = s2; }
    __syncthreads();
    if (t == 0) {
        float S  = ls[0] + ls[1] + ls[2] + ls[3];
        float S2 = ls2[0] + ls2[1] + ls2[2] + ls2[3];
        float inv_n = 1.f / (float)n;
        float mu  = S * inv_n;
        float var = S2 * inv_n - mu * mu;
        mu_out[ci] = mu;
        rs_out[ci] = rsqrtf(var + EPS);
    }
}

// ---------------- q/k/v projections (W staged in LDS) ----------------
__global__ __launch_bounds__(512) void qkv_kernel(const float* __restrict__ x,
                                                  const float* __restrict__ skip,
                                                  const float* __restrict__ Wq, const float* __restrict__ bq,
                                                  const float* __restrict__ Wk, const float* __restrict__ bk,
                                                  const float* __restrict__ Wv, const float* __restrict__ bv,
                                                  const float* __restrict__ ws,
                                                  float* __restrict__ q_out,
                                                  float* __restrict__ k_out,
                                                  float* __restrict__ v_out) {
    __shared__ float a[64 * 129];
    __shared__ float wl[128 * 64];
    int t = threadIdx.x;
    int which = blockIdx.y;
    int half  = blockIdx.z;
    int n0 = blockIdx.x * 64;

    const float* W = (which == 0) ? Wq : (which == 1) ? Wk : Wv;
    const float* b = (which == 0) ? bq : (which == 1) ? bk : bv;
    float* outp    = (which == 0) ? q_out : (which == 1) ? k_out : v_out;
    float scale    = (which == 0) ? 0.25f : 1.0f;

    {
        const float4* W4 = (const float4*)W;
        float4* wl4 = (float4*)wl;
        for (int i4 = t; i4 < 2048; i4 += 512) {
            int ci = i4 >> 4, j4 = i4 & 15;
            wl4[ci * 16 + j4] = W4[ci * 32 + half * 16 + j4];
        }
    }
    if (which == 0) {
        const float* mu = ws;       const float* rs = ws + DIM;
        for (int idx = t; idx < 8192; idx += 512) {
            int ci = idx >> 6, ln = idx & 63;
            int n = n0 + ln;
            int hc = n >> 8, wc = (n >> 3) & 31, zc = n & 7;
            float v = x[ci * 1024 + (hc >> 1) * 64 + (wc >> 1) * 4 + (zc >> 1)];
            a[ln * 129 + ci] = (v - mu[ci]) * rs[ci];
        }
    } else {
        const float* mu = ws + 2*DIM; const float* rs = ws + 3*DIM;
        for (int idx = t; idx < 8192; idx += 512) {
            int ci = idx >> 6, ln = idx & 63;
            float v = skip[(size_t)ci * NPOS + n0 + ln];
            a[ln * 129 + ci] = (v - mu[ci]) * rs[ci];
        }
    }
    __syncthreads();

    int ln = t & 63, ch = t >> 6;
    float acc[8];
    #pragma unroll
    for (int j = 0; j < 8; ++j) acc[j] = b[half * 64 + ch * 8 + j];
    for (int ci = 0; ci < 128; ++ci) {
        float av = a[ln * 129 + ci];
        const float4* wr = (const float4*)(wl + ci * 64 + ch * 8);
        float4 w0 = wr[0], w1 = wr[1];
        acc[0] = fmaf(av, w0.x, acc[0]);
        acc[1] = fmaf(av, w0.y, acc[1]);
        acc[2] = fmaf(av, w0.z, acc[2]);
        acc[3] = fmaf(av, w0.w, acc[3]);
        acc[4] = fmaf(av, w1.x, acc[4]);
        acc[5] = fmaf(av, w1.y, acc[5]);
        acc[6] = fmaf(av, w1.z, acc[6]);
        acc[7] = fmaf(av, w1.w, acc[7]);
    }
    float* op = outp + (size_t)(n0 + ln) * 128 + half * 64 + ch * 8;
    *(float4*)(op + 0) = make_float4(acc[0]*scale, acc[1]*scale, acc[2]*scale, acc[3]*scale);
    *(float4*)(op + 4) = make_float4(acc[4]*scale, acc[5]*scale, acc[6]*scale, acc[7]*scale);
}

// ---------------- neighborhood attention: LDS-tiled, bf16 k/v ----------------
// Block = (4x4x8 tile, head). Halo 8x8x8=512. k/v stored bf16 in LDS:
// chunk c (dims 8c..8c+7) of nbr at kbf + c*4104 + nbr*8 (ushorts) -> 16B
// aligned, 16B-channel = (513c + nbr) % 8 -> uniform spread.
// 4 lanes/position, neighbors processed in PAIRS (one rescale per 2 nbrs).
// LDS ~45KB -> 3 blocks/CU.
__global__ __launch_bounds__(512) void attn_kernel(const float* __restrict__ q,
                                                   const float* __restrict__ k,
                                                   const float* __restrict__ v,
                                                   const float* __restrict__ rpb,
                                                   float* __restrict__ ao) {
    __shared__ __align__(16) unsigned short kbf[2 * 513 * 8];  // 16416 B
    __shared__ __align__(16) unsigned short vbf[2 * 513 * 8];  // 16416 B
    __shared__ float qT[128 * 20];                             // 10240 B
    __shared__ float bias_l[729];                              // 2916 B

    int blk = blockIdx.x;
    int h    = blk & 7;
    int tile = blk >> 3;
    int h0 = (tile >> 3) * 4;
    int w0 = (tile & 7) * 4;
    int bh0 = min(max(h0 - 2, 0), 24);
    int bw0 = min(max(w0 - 2, 0), 24);
    int t = threadIdx.x;

    // ---- stage k, v halo as bf16 ----
    for (int idx = t; idx < 2048; idx += 512) {
        int nbr = idx >> 2, d4 = idx & 3;
        int nh = bh0 + (nbr >> 6);
        int nw = bw0 + ((nbr >> 3) & 7);
        int nz = nbr & 7;
        int n  = nh * 256 + nw * 8 + nz;
        float4 kk = *(const float4*)(k + (size_t)n * 128 + h * 16 + d4 * 4);
        float4 vv = *(const float4*)(v + (size_t)n * 128 + h * 16 + d4 * 4);
        int c = d4 >> 1, sub = (d4 & 1) * 4;
        ushort4 k4; k4.x = f2bf(kk.x); k4.y = f2bf(kk.y); k4.z = f2bf(kk.z); k4.w = f2bf(kk.w);
        ushort4 v4; v4.x = f2bf(vv.x); v4.y = f2bf(vv.y); v4.z = f2bf(vv.z); v4.w = f2bf(vv.w);
        *(ushort4*)(kbf + c * 4104 + nbr * 8 + sub) = k4;
        *(ushort4*)(vbf + c * 4104 + nbr * 8 + sub) = v4;
    }
    // ---- stage q tile (fp32) ----
    {
        int p = t >> 2, d4 = t & 3;
        int n = (h0 + (p >> 5)) * 256 + (w0 + ((p >> 3) & 3)) * 8 + (p & 7);
        float4 qq = *(const float4*)(q + (size_t)n * 128 + h * 16 + d4 * 4);
        *(float4*)(qT + p * 20 + d4 * 4) = qq;
    }
    for (int idx = t; idx < 729; idx += 512) bias_l[idx] = rpb[h * 729 + idx];
    __syncthreads();

    int s = t & 3, p = t >> 2;
    int ph = p >> 5, pw = (p >> 3) & 3, pz = p & 7;
    int hc = h0 + ph, wc = w0 + pw, zc = pz;
    int sh = min(max(hc - 2, 0), 27);
    int sw = min(max(wc - 2, 0), 27);
    int sz = min(max(zc - 2, 0), 3);
    int base_nbr  = (sh - bh0) * 64 + (sw - bw0) * 8 + sz;
    int bias_base = (sh - hc + 4) * 81 + (sw - wc + 4) * 9 + (sz - zc + 4);

    float qv[16];
    #pragma unroll
    for (int i = 0; i < 4; ++i) ((float4*)qv)[i] = *(const float4*)(qT + p * 20 + i * 4);

    float o[16];
    #pragma unroll
    for (int d = 0; d < 16; ++d) o[d] = 0.f;
    float m = -1e30f, l = 0.f;

    int cnt = (s == 0) ? 32 : 31;

    // helpers as lambdas (inlined)
    auto score_of = [&](int j, int& nbr_out) -> float {
        int jh = (j * 41) >> 10;
        int jr = j - jh * 25;
        int jw = (jr * 13) >> 6;
        int jz = jr - jw * 5;
        int nbr = base_nbr + jh * 64 + jw * 8 + jz;
        nbr_out = nbr;
        float bias = bias_l[bias_base + jh * 81 + jw * 9 + jz];
        uint4 ka = *(const uint4*)(kbf + nbr * 8);
        uint4 kb = *(const uint4*)(kbf + 4104 + nbr * 8);
        float d0 = 0.f, d1 = 0.f, d2 = 0.f, d3 = 0.f;
        d0 = fmaf(__uint_as_float(ka.x << 16),         qv[0],  d0);
        d0 = fmaf(__uint_as_float(ka.x & 0xffff0000u), qv[1],  d0);
        d0 = fmaf(__uint_as_float(ka.y << 16),         qv[2],  d0);
        d0 = fmaf(__uint_as_float(ka.y & 0xffff0000u), qv[3],  d0);
        d1 = fmaf(__uint_as_float(ka.z << 16),         qv[4],  d1);
        d1 = fmaf(__uint_as_float(ka.z & 0xffff0000u), qv[5],  d1);
        d1 = fmaf(__uint_as_float(ka.w << 16),         qv[6],  d1);
        d1 = fmaf(__uint_as_float(ka.w & 0xffff0000u), qv[7],  d1);
        d2 = fmaf(__uint_as_float(kb.x << 16),         qv[8],  d2);
        d2 = fmaf(__uint_as_float(kb.x & 0xffff0000u), qv[9],  d2);
        d2 = fmaf(__uint_as_float(kb.y << 16),         qv[10], d2);
        d2 = fmaf(__uint_as_float(kb.y & 0xffff0000u), qv[11], d2);
        d3 = fmaf(__uint_as_float(kb.z << 16),         qv[12], d3);
        d3 = fmaf(__uint_as_float(kb.z & 0xffff0000u), qv[13], d3);
        d3 = fmaf(__uint_as_float(kb.w << 16),         qv[14], d3);
        d3 = fmaf(__uint_as_float(kb.w & 0xffff0000u), qv[15], d3);
        return (d0 + d1) + (d2 + d3) + bias;
    };
    auto load_v = [&](int nbr, float* vv) {
        uint4 va = *(const uint4*)(vbf + nbr * 8);
        uint4 vb = *(const uint4*)(vbf + 4104 + nbr * 8);
        vv[0]  = __uint_as_float(va.x << 16); vv[1]  = __uint_as_float(va.x & 0xffff0000u);
        vv[2]  = __uint_as_float(va.y << 16); vv[3]  = __uint_as_float(va.y & 0xffff0000u);
        vv[4]  = __uint_as_float(va.z << 16); vv[5]  = __uint_as_float(va.z & 0xffff0000u);
        vv[6]  = __uint_as_float(va.w << 16); vv[7]  = __uint_as_float(va.w & 0xffff0000u);
        vv[8]  = __uint_as_float(vb.x << 16); vv[9]  = __uint_as_float(vb.x & 0xffff0000u);
        vv[10] = __uint_as_float(vb.y << 16); vv[11] = __uint_as_float(vb.y & 0xffff0000u);
        vv[12] = __uint_as_float(vb.z << 16); vv[13] = __uint_as_float(vb.z & 0xffff0000u);
        vv[14] = __uint_as_float(vb.w << 16); vv[15] = __uint_as_float(vb.w & 0xffff0000u);
    };

    int ii = 0;
    for (; ii + 1 < cnt; ii += 2) {
        int nbr1, nbr2;
        float s1 = score_of(4 * ii + s, nbr1);
        float s2 = score_of(4 * (ii + 1) + s, nbr2);
        float v1[16], v2[16];
        load_v(nbr1, v1);
        load_v(nbr2, v2);
        float mn = fmaxf(m, fmaxf(s1, s2));
        float a  = __expf(m - mn);
        float p1 = __expf(s1 - mn);
        float p2 = __expf(s2 - mn);
        l = fmaf(l, a, p1 + p2);
        #pragma unroll
        for (int d = 0; d < 16; ++d)
            o[d] = fmaf(o[d], a, fmaf(p1, v1[d], p2 * v2[d]));
        m = mn;
    }
    if (ii < cnt) {
        int nbr1;
        float s1 = score_of(4 * ii + s, nbr1);
        float v1[16];
        load_v(nbr1, v1);
        float mn = fmaxf(m, s1);
        float a  = __expf(m - mn);
        float p1 = __expf(s1 - mn);
        l = fmaf(l, a, p1);
        #pragma unroll
        for (int d = 0; d < 16; ++d) o[d] = fmaf(o[d], a, p1 * v1[d]);
        m = mn;
    }

    // ---- merge the 4 slots ----
    #pragma unroll
    for (int step = 1; step <= 2; step <<= 1) {
        float m2 = __shfl_xor(m, step, 64);
        float l2 = __shfl_xor(l, step, 64);
        float mn = fmaxf(m, m2);
        float a = __expf(m - mn);
        float b = __expf(m2 - mn);
        l = l * a + l2 * b;
        #pragma unroll
        for (int d = 0; d < 16; ++d) {
            float od = __shfl_xor(o[d], step, 64);
            o[d] = o[d] * a + od * b;
        }
        m = mn;
    }
    float inv = 1.f / l;
    int n = hc * 256 + wc * 8 + zc;
    float4 r = make_float4(o[4*s] * inv, o[4*s+1] * inv, o[4*s+2] * inv, o[4*s+3] * inv);
    *(float4*)(ao + (size_t)n * 128 + h * 16 + s * 4) = r;
}

// ---------------- output projection (Wo staged in LDS) ----------------
__global__ __launch_bounds__(512) void proj_kernel(const float* __restrict__ ao,
                                                   const float* __restrict__ Wo,
                                                   const float* __restrict__ bo,
                                                   float* __restrict__ out) {
    __shared__ float a[64 * 129];
    __shared__ float wl[128 * 64];
    int t = threadIdx.x;
    int half = blockIdx.y;
    int n0 = blockIdx.x * 64;

    {
        const float4* W4 = (const float4*)Wo;
        float4* wl4 = (float4*)wl;
        for (int i4 = t; i4 < 2048; i4 += 512) {
            int ci = i4 >> 4, j4 = i4 & 15;
            wl4[ci * 16 + j4] = W4[ci * 32 + half * 16 + j4];
        }
    }
    for (int idx = t; idx < 8192; idx += 512) {
        int ln = idx >> 7, ci = idx & 127;
        a[ln * 129 + ci] = ao[(size_t)n0 * 128 + idx];
    }
    __syncthreads();

    int ln = t & 63, ch = t >> 6;
    float acc[8];
    #pragma unroll
    for (int j = 0; j < 8; ++j) acc[j] = bo[half * 64 + ch * 8 + j];
    for (int ci = 0; ci < 128; ++ci) {
        float av = a[ln * 129 + ci];
        const float4* wr = (const float4*)(wl + ci * 64 + ch * 8);
        float4 w0 = wr[0], w1 = wr[1];
        acc[0] = fmaf(av, w0.x, acc[0]);
        acc[1] = fmaf(av, w0.y, acc[1]);
        acc[2] = fmaf(av, w0.z, acc[2]);
        acc[3] = fmaf(av, w0.w, acc[3]);
        acc[4] = fmaf(av, w1.x, acc[4]);
        acc[5] = fmaf(av, w1.y, acc[5]);
        acc[6] = fmaf(av, w1.z, acc[6]);
        acc[7] = fmaf(av, w1.w, acc[7]);
    }
    #pragma unroll
    for (int j = 0; j < 8; ++j)
        out[(size_t)(half * 64 + ch * 8 + j) * NPOS + n0 + ln] = acc[j];
}

extern "C" void kernel_launch(void* const* d_in, const int* in_sizes, int n_in,
                              void* d_out, int out_size, void* d_ws, size_t ws_size,
                              hipStream_t stream) {
    const float* x    = (const float*)d_in[0];
    const float* skip = (const float*)d_in[1];
    const float* Wq   = (const float*)d_in[2];
    const float* bq   = (const float*)d_in[3];
    const float* Wk   = (const float*)d_in[4];
    const float* bk   = (const float*)d_in[5];
    const float* Wv   = (const float*)d_in[6];
    const float* bv   = (const float*)d_in[7];
    const float* rpb  = (const float*)d_in[8];
    const float* Wo   = (const float*)d_in[9];
    const float* bo   = (const float*)d_in[10];
    float* out = (float*)d_out;

    float* ws  = (float*)d_ws;
    float* q   = ws + 512;
    float* k   = q  + (size_t)NPOS * 128;
    float* v   = k  + (size_t)NPOS * 128;
    float* ao  = v  + (size_t)NPOS * 128;

    stats_kernel<<<256, 256, 0, stream>>>(x, skip, ws);
    qkv_kernel<<<dim3(128, 3, 2), 512, 0, stream>>>(x, skip, Wq, bq, Wk, bk, Wv, bv, ws, q, k, v);
    attn_kernel<<<512, 512, 0, stream>>>(q, k, v, rpb, ao);
    proj_kernel<<<dim3(128, 2), 512, 0, stream>>>(ao, Wo, bo, out);
}